// Round 1
// 9234.703 us; speedup vs baseline: 1.7812x; 1.7812x over previous
//
#include <hip/hip_runtime.h>

typedef _Float16 f16;
typedef _Float16 f16x2 __attribute__((ext_vector_type(2)));
typedef _Float16 f16x8 __attribute__((ext_vector_type(8)));
typedef float    f32x4 __attribute__((ext_vector_type(4)));

// ---------------- static device scratch (avoids ws_size assumptions) --------
__device__ f16   g_Xpad [64u*1028u*512u];   // conv1 input (B,T+4,512): ch0-255 coarse, 256-511 fine(final)
__device__ f16   g_fseqA[64u*1024u*256u];   // fine sequence ping
__device__ f16   g_fseqB[64u*1024u*256u];   // fine sequence pong
__device__ float g_xg32 [64u*1024u*1024u];  // per-f-layer input projection, permuted gate order, fp32
__device__ f16   g_c2in [64u*1026u*256u];   // conv2 input (B,T+2,256), padded
__device__ f16   g_c3in [64u*1024u*128u];   // conv3 input (B,T,128)
// whh octet-major layout: [L][ko:32][r:1024][kl:8]; k = ko*8+kl, r = u*4+q (orig row g=q*256+u)
__device__ f16   g_whhT2[5u*262144u];
__device__ f16   g_wihB [3u*262144u];       // [l][g'][k] fp16, permuted gate rows (g' = u*4+q)
__device__ float g_biasP[3*1024];           // permuted bih+bhh for f1..f3
__device__ f16   g_B1   [256u*2560u];       // conv1 weight as GEMM B [oc][r*512+ic]
__device__ f16   g_B2   [128u*768u];        // conv2 weight as GEMM B [oc][r*256+ic]
__device__ float g_xg0  [2*64*1024];        // static xg for coarse/f0, permuted [u*4+q]
__device__ float g_cat512[64*512];          // [h, le]
__device__ float g_h    [64*256];
__device__ float g_feats[64*512];           // [coarse.mean, fine.mean]
__device__ float g_osc  [64*1024];
__device__ float g_smean[1024];
__device__ float g_cpar [64*4];             // raw cp sigmoid outputs
__device__ float g_enh  [64*1024];
// h-exchange mailboxes for the 4-block cooperative LSTM:
// [L:5][b:64][parity:2][part:4][slot:32] u64 = (tag:step+1)<<32 | f16x2(h[2s],h[2s+1])
// tag+data travel in ONE atomic word -> no fence/ordering subtleties.
// zeroed every launch in k_zero (graph-replay safe).
__device__ unsigned long long g_hx[81920];

// ---------------- helpers ---------------------------------------------------
__device__ inline float fdot2f(f16x2 a, f16x2 b, float c) {
#if __has_builtin(__builtin_amdgcn_fdot2)
  return __builtin_amdgcn_fdot2(a, b, c, false);
#else
  return c + (float)a[0]*(float)b[0] + (float)a[1]*(float)b[1];
#endif
}
__device__ inline float sigm_fast(float x) { return 1.0f / (1.0f + __expf(-x)); }
__device__ inline float tanh_fast(float x) { float e = __expf(2.0f*x); return 1.0f - 2.0f/(e + 1.0f); }
__device__ inline float lrelu(float x) { return x < 0.0f ? 0.2f*x : x; }

__device__ __forceinline__ void dot8x(f16x8 w, f16x8 h, float& a) {
  a = fdot2f(__builtin_shufflevector(w, w, 0, 1), __builtin_shufflevector(h, h, 0, 1), a);
  a = fdot2f(__builtin_shufflevector(w, w, 2, 3), __builtin_shufflevector(h, h, 2, 3), a);
  a = fdot2f(__builtin_shufflevector(w, w, 4, 5), __builtin_shufflevector(h, h, 4, 5), a);
  a = fdot2f(__builtin_shufflevector(w, w, 6, 7), __builtin_shufflevector(h, h, 6, 7), a);
}

// ---------------- weight prep ----------------------------------------------
__global__ void __launch_bounds__(256) k_prep_whh(const float* cw, const float* f0w, const float* fw) {
  int bid = blockIdx.x;               // 5*1024
  int L = bid >> 10, g = bid & 1023, k = threadIdx.x;
  const float* src = (L == 0) ? cw : (L == 1) ? f0w : (fw + (size_t)(L-2)*262144u);
  int q = g >> 8, u = g & 255, r = u*4 + q;
  int ko = k >> 3, kl = k & 7;
  g_whhT2[(size_t)L*262144u + (size_t)(ko*1024 + r)*8u + kl] = (f16)src[(size_t)g*256 + k];
}
__global__ void __launch_bounds__(256) k_prep_wih(const float* fwih, const float* fbih, const float* fbhh) {
  int bid = blockIdx.x;               // 3*1024
  int L = bid >> 10, gp = bid & 1023, k = threadIdx.x;
  int j = gp >> 2, q = gp & 3, g = q*256 + j;
  g_wihB[(size_t)L*262144u + (size_t)gp*256u + k] = (f16)fwih[(size_t)L*262144u + (size_t)g*256u + k];
  if (k == 0) g_biasP[L*1024 + gp] = fbih[L*1024 + g] + fbhh[L*1024 + g];
}
__global__ void __launch_bounds__(256) k_prep_c1(const float* w) {
  int idx = blockIdx.x*256 + threadIdx.x;        // 655360
  int oc = idx / 2560, rem = idx % 2560, r = rem / 512, ic = rem % 512;
  g_B1[idx] = (f16)w[(size_t)oc*2560 + (size_t)ic*5 + r];
}
__global__ void __launch_bounds__(256) k_prep_c2(const float* w) {
  int idx = blockIdx.x*256 + threadIdx.x;        // 98304
  int oc = idx / 768, rem = idx % 768, r = rem / 256, ic = rem % 256;
  g_B2[idx] = (f16)w[(size_t)oc*768 + (size_t)ic*3 + r];
}
__global__ void __launch_bounds__(256) k_zero() {
  int idx = blockIdx.x*256 + threadIdx.x;        // 245760
  if (idx < 131072) {   // Xpad pad rows 0,1,1026,1027
    int b = idx >> 11, rem = idx & 2047, rr = rem >> 9, c = rem & 511;
    int row = (rr < 2) ? rr : 1024 + rr;
    g_Xpad[(size_t)b*526336u + (size_t)row*512u + c] = (f16)0.0f;
  } else if (idx < 163840) {   // c2in pad rows 0, 1025
    int i2 = idx - 131072;
    int b = i2 >> 9, rem = i2 & 511, rr = rem >> 8, c = rem & 255;
    int row = rr ? 1025 : 0;
    g_c2in[(size_t)b*262656u + (size_t)row*256u + c] = (f16)0.0f;
  } else {              // h-exchange tags: must be reset each launch
    g_hx[idx - 163840] = 0ull;
  }
}

// ---------------- small front-end ops ---------------------------------------
__global__ void __launch_bounds__(256) k_setup1(const float* z, const int* labels, const float* emb,
                                                const float* npw, const float* npb,
                                                const float* lg, const float* lb) {
  __shared__ float x[384];
  __shared__ float s1[256], s2[256];
  int b = blockIdx.x, tid = threadIdx.x;
  int lab = labels[b];
  for (int i = tid; i < 384; i += 256)
    x[i] = (i < 128) ? z[b*128 + i] : emb[lab*256 + (i - 128)];
  __syncthreads();
  float acc = npb[tid];
  for (int k = 0; k < 384; ++k) acc += npw[tid*384 + k]*x[k];
  s1[tid] = acc; s2[tid] = acc*acc; __syncthreads();
  for (int s = 128; s > 0; s >>= 1) { if (tid < s) { s1[tid]+=s1[tid+s]; s2[tid]+=s2[tid+s]; } __syncthreads(); }
  float m = s1[0]*(1.0f/256.0f), var = s2[0]*(1.0f/256.0f) - m*m;
  float hv = (acc - m)*(1.0f/sqrtf(var + 1e-5f))*lg[tid] + lb[tid];
  hv = lrelu(hv);
  g_h[b*256 + tid] = hv;
  g_cat512[b*512 + tid] = hv;
  g_cat512[b*512 + 256 + tid] = x[128 + tid];
}
__global__ void __launch_bounds__(1024) k_xg0(const float* cwih, const float* cbih, const float* cbhh,
                                              const float* fwih, const float* fbih, const float* fbhh) {
  int bid = blockIdx.x;               // 128 = layer*64+b
  int layer = bid >> 6, b = bid & 63;
  int gp = threadIdx.x, j = gp >> 2, q = gp & 3, g = q*256 + j;
  __shared__ float cat[512];
  if (gp < 512) cat[gp] = g_cat512[b*512 + gp];
  __syncthreads();
  const float* w = layer ? fwih : cwih;
  float acc = layer ? (fbih[g] + fbhh[g]) : (cbih[g] + cbhh[g]);
  for (int k = 0; k < 512; ++k) acc += w[(size_t)g*512 + k]*cat[k];
  g_xg0[(layer*64 + b)*1024 + gp] = acc;
}
__global__ void __launch_bounds__(256) k_osc(const float* w1, const float* b1v, const float* lg,
                                             const float* lb, const float* w2, const float* b2v) {
  __shared__ float hb[256], av[256], s1[256], s2[256];
  int b = blockIdx.x, tid = threadIdx.x;
  hb[tid] = g_h[b*256 + tid];
  __syncthreads();
  float acc = b1v[tid];
  for (int k = 0; k < 256; ++k) acc += w1[tid*256 + k]*hb[k];
  s1[tid] = acc; s2[tid] = acc*acc; __syncthreads();
  for (int s = 128; s > 0; s >>= 1) { if (tid < s) { s1[tid]+=s1[tid+s]; s2[tid]+=s2[tid+s]; } __syncthreads(); }
  float m = s1[0]*(1.0f/256.0f), var = s2[0]*(1.0f/256.0f) - m*m;
  av[tid] = lrelu((acc - m)*(1.0f/sqrtf(var + 1e-5f))*lg[tid] + lb[tid]);
  __syncthreads();
  for (int tt = tid; tt < 1024; tt += 256) {
    float o = b2v[tt];
    for (int i = 0; i < 256; ++i) o += w2[(size_t)tt*256 + i]*av[i];
    g_osc[b*1024 + tt] = tanhf(o);
  }
}
__global__ void __launch_bounds__(256) k_sinmean(const float* sw, const float* sb) {
  int tt = blockIdx.x*256 + threadIdx.x;   // grid 4
  const float F[6] = {0.19f, 0.21f, 0.23f, 0.25f, 0.27f, 0.29f};
  float tl = tt*(1.0f/1023.0f);
  float sc[12];
  for (int j = 0; j < 6; ++j) {
    float p = (6.2831853071795864f * tl) * F[j] * 1024.0f;
    sc[j] = sinf(p); sc[6 + j] = cosf(p);
  }
  float a = 0.0f;
  for (int i = 0; i < 128; ++i) {
    float s = sb[i];
    for (int j = 0; j < 12; ++j) s += sw[i*12 + j]*sc[j];
    a += s;
  }
  g_smean[tt] = a*(1.0f/128.0f);
}

// ---------------- cooperative LSTM core -------------------------------------
// One sequence (batch b) is split across 4 blocks ("parts"); part p owns
// permuted gate rows [256p, 256p+256) = hidden units [64p, 64p+64).
// The 128 KB weight slice lives ENTIRELY in VGPRs (64 regs/thread, loaded
// once, loop-invariant -- unlike the streamed-residency attempts the compiler
// demoted in R2/R4/R6/R7). Zero weight traffic per step.
// Per step: 512 threads compute half-row partials (thread tau: row tau&255,
// k-half tau>>8) -> gbuf -> wave0 (64 threads) does the gate update and owns
// c,h; h slices are exchanged between the 4 parts via tagged u64 agent-scope
// atomics (tag=step+1 in hi32, f16x2 h-pair in lo32; step-parity double
// buffer). Lockstep argument: a part can only overwrite a parity slot two
// steps later, which requires it to have gathered every peer's NEXT tag,
// which requires every peer to have consumed the old one. Threads 64..159
// gather the 96 peer slots into hbuf while wave0 publishes.
// Co-residency: grid = 256 blocks, __launch_bounds__(512,2) caps VGPR<=256 so
// every block is schedulable at 1 block/CU; 256 blocks <= 256 CUs -> all
// resident -> spin-wait cannot deadlock. gbuf padded to 96KB LDS to force
// 1 block/CU (dedicated VALU+LDS per part).
__global__ void __launch_bounds__(512, 2) k_lstm(int L, int xsel, int osel) {
  // L: weight layer 0..4 in g_whhT2 (coarse,f0,f1,f2,f3)
  // xsel: 0/1 -> g_xg0 layer (constant per step), 2 -> g_xg32 (per step)
  // osel: 0=Xpad ch0+feats, 1=fseqA, 2=fseqB, 3=fseqA, 4=Xpad ch256+feats
  int bid = blockIdx.x;
  int b = bid & 63, p = bid >> 6;    // parts of a batch land on one XCD (%8)
  int tau = threadIdx.x;
  int j = tau & 255, kh = tau >> 8;
  const f16* Wc = g_whhT2 + (size_t)L*262144u;

  __shared__ __align__(16) f16 hbuf[2][256];
  __shared__ __align__(16) float gbuf[24576];   // only [0,512) used; pads LDS to force 1 block/CU

  // ---- weights -> registers: rows r=256p+j, k in [128*kh, 128*kh+128)
  // g_whhT2 layout [ko][r][8]: consecutive lanes (consecutive j/r) -> 16B-contiguous: coalesced.
  f16x8 w[16];
  {
    const f16* wp = Wc + (size_t)(kh*16*1024 + 256*p + j)*8u;
#pragma unroll
    for (int i = 0; i < 16; ++i) w[i] = *(const f16x8*)(wp + (size_t)i*8192u);
  }

  if (tau < 256) hbuf[0][tau] = (f16)0.0f;

  float c0 = 0.0f, sum0 = 0.0f;
  f32x4 xv = {0.f, 0.f, 0.f, 0.f};
  const float* xgp = nullptr;
  f16* outp = nullptr; int ostride = 0;
  unsigned long long* hx_my = nullptr;
  const unsigned long long* hx_src = nullptr;
  int gdst = 0;
  if (tau < 64) {                      // wave 0: unit owners (unit u = 64p+tau)
    int ch = 64*p + tau;
    if (xsel < 2) {
      xv = *(const f32x4*)(g_xg0 + (size_t)(xsel*64 + b)*1024u + 256*p + 4*tau);
    } else {
      xgp = g_xg32 + (size_t)b*1048576u + 256*p + 4*tau;
      xv = *(const f32x4*)xgp;
    }
    if (osel == 0)      { outp = g_Xpad  + (size_t)b*526336u + 1024 + ch;       ostride = 512; }
    else if (osel == 1) { outp = g_fseqA + (size_t)b*262144u + ch;              ostride = 256; }
    else if (osel == 2) { outp = g_fseqB + (size_t)b*262144u + ch;              ostride = 256; }
    else if (osel == 3) { outp = g_fseqA + (size_t)b*262144u + ch;              ostride = 256; }
    else                { outp = g_Xpad  + (size_t)b*526336u + 1024 + 256 + ch; ostride = 512; }
    hx_my = g_hx + ((size_t)((L*64 + b)*8 + p))*32u + (tau >> 1);
  } else if (tau < 160) {              // gather threads: 96 peer slots
    int gi = tau - 64;
    int ppsel = gi >> 5;
    int pp = ppsel + (ppsel >= p ? 1 : 0);
    int sl = gi & 31;
    hx_src = g_hx + ((size_t)((L*64 + b)*8 + pp))*32u + sl;
    gdst = 64*pp + 2*sl;
  }
  __syncthreads();

  int cur = 0;
#pragma unroll 1
  for (int step = 0; step < 1024; ++step) {
    // ---- partial dot: row 256p+j over k-half kh (weights in regs, h broadcast from LDS)
    const f16* hb = &hbuf[cur][kh*128];
    float acc = 0.0f;
#pragma unroll
    for (int i = 0; i < 16; ++i) {
      f16x8 hv = *(const f16x8*)(hb + i*8);
      dot8x(w[i], hv, acc);
    }
    gbuf[tau] = acc;
    __syncthreads();
    bool notlast = (step < 1023);
    if (tau < 64) {
      f32x4 g0 = *(const f32x4*)(&gbuf[4*tau]);          // kh=0 partials, rows 4u..4u+3
      f32x4 g1 = *(const f32x4*)(&gbuf[256 + 4*tau]);    // kh=1 partials
      float ii = sigm_fast(g0[0] + g1[0] + xv[0]);
      float ff = sigm_fast(g0[1] + g1[1] + xv[1]);
      float gg = tanh_fast(g0[2] + g1[2] + xv[2]);
      float oo = sigm_fast(g0[3] + g1[3] + xv[3]);
      c0 = ff*c0 + ii*gg;
      float h0 = oo*tanh_fast(c0);
      sum0 += h0;
      f16 hh = (f16)h0;
      hbuf[cur ^ 1][64*p + tau] = hh;                    // own slice, local
      outp[(size_t)step*ostride] = hh;
      float hn = __shfl_down(h0, 1);                     // whole wave0 executes
      if (notlast) {
        if ((tau & 1) == 0) {                            // 32 publishers
          f16x2 pk; pk[0] = hh; pk[1] = (f16)hn;
          unsigned long long val = ((unsigned long long)(unsigned)(step + 1) << 32)
                                 | (unsigned long long)__builtin_bit_cast(unsigned int, pk);
          __hip_atomic_store(hx_my + (size_t)(step & 1)*128u, val,
                             __ATOMIC_RELAXED, __HIP_MEMORY_SCOPE_AGENT);
        }
        if (xsel == 2) xv = *(const f32x4*)(xgp + (size_t)(step + 1)*1024u);  // prefetch next xg
      }
    } else if (tau < 160 && notlast) {
      unsigned int want = (unsigned)(step + 1);
      const unsigned long long* sp = hx_src + (size_t)(step & 1)*128u;
      unsigned long long v;
      do {
        v = __hip_atomic_load(sp, __ATOMIC_RELAXED, __HIP_MEMORY_SCOPE_AGENT);
      } while ((unsigned)(v >> 32) != want);
      *(f16x2*)(&hbuf[cur ^ 1][gdst]) = __builtin_bit_cast(f16x2, (unsigned)v);
    }
    __syncthreads();
    cur ^= 1;
  }
  if (tau < 64) {
    int ch = 64*p + tau;
    if (osel == 0) g_feats[b*512 + ch]       = sum0*(1.0f/1024.0f);
    if (osel == 4) g_feats[b*512 + 256 + ch] = sum0*(1.0f/1024.0f);
  }
}

// ---------------- generic fp16 MFMA GEMM (implicit conv / xg projection) ----
__global__ void __launch_bounds__(256) k_gemm(int which, int l,
                                              const float* cb, const float* bng, const float* bnb) {
  const f16* A; size_t a_bs; int a_rs, K, N; const f16* Bm; int mode;
  float* outF = nullptr; f16* outH = nullptr; size_t o_bs; int o_rs;
  const float* bias;
  if (which <= 1) {
    A = (which == 0) ? g_fseqA : g_fseqB; a_bs = 262144u; a_rs = 256; K = 256; N = 1024;
    Bm = g_wihB + (size_t)l*262144u; mode = 0; bias = g_biasP + l*1024;
    outF = g_xg32; o_bs = 1048576u; o_rs = 1024;
  } else if (which == 2) {
    A = g_Xpad; a_bs = 526336u; a_rs = 512; K = 2560; N = 256; Bm = g_B1; mode = 1; bias = cb;
    outH = g_c2in + 256; o_bs = 262656u; o_rs = 256;
  } else {
    A = g_c2in; a_bs = 262656u; a_rs = 256; K = 768; N = 128; Bm = g_B2; mode = 1; bias = cb;
    outH = g_c3in; o_bs = 131072u; o_rs = 128;
  }
  int tid = threadIdx.x, wave = tid >> 6, lane = tid & 63;
  int m0 = blockIdx.x*128, n0 = blockIdx.y*64;
  __shared__ __align__(16) f16 Asm[128*72];
  __shared__ __align__(16) f16 Bsm[64*72];
  f32x4 acc[2][4];
#pragma unroll
  for (int i = 0; i < 2; ++i)
#pragma unroll
    for (int jj = 0; jj < 4; ++jj) { f32x4 zz = {0.f,0.f,0.f,0.f}; acc[i][jj] = zz; }
  int ar = tid & 127, ac = (tid >> 7)*32;
  int mrow = m0 + ar, abb = mrow >> 10, att = mrow & 1023;
  const f16* aptr = A + (size_t)abb*a_bs + (size_t)att*a_rs + ac;
  int br = tid & 63, bc = (tid >> 6)*16;
  const f16* bptr = Bm + (size_t)(n0 + br)*K + bc;
  int nkb = K >> 6;
  for (int kb = 0; kb < nkb; ++kb) {
    f16x8 av0 = *(const f16x8*)(aptr + 0);
    f16x8 av1 = *(const f16x8*)(aptr + 8);
    f16x8 av2 = *(const f16x8*)(aptr + 16);
    f16x8 av3 = *(const f16x8*)(aptr + 24);
    f16x8 bv0 = *(const f16x8*)(bptr + 0);
    f16x8 bv1 = *(const f16x8*)(bptr + 8);
    aptr += 64; bptr += 64;
    __syncthreads();
    *(f16x8*)(&Asm[ar*72 + ac + 0])  = av0;
    *(f16x8*)(&Asm[ar*72 + ac + 8])  = av1;
    *(f16x8*)(&Asm[ar*72 + ac + 16]) = av2;
    *(f16x8*)(&Asm[ar*72 + ac + 24]) = av3;
    *(f16x8*)(&Bsm[br*72 + bc + 0])  = bv0;
    *(f16x8*)(&Bsm[br*72 + bc + 8])  = bv1;
    __syncthreads();
#pragma unroll
    for (int ks = 0; ks < 2; ++ks) {
      int ko = ks*32 + (lane >> 4)*8;
      f16x8 a0 = *(const f16x8*)(&Asm[(wave*32 + (lane & 15))*72 + ko]);
      f16x8 a1 = *(const f16x8*)(&Asm[(wave*32 + 16 + (lane & 15))*72 + ko]);
#pragma unroll
      for (int nt = 0; nt < 4; ++nt) {
        f16x8 bf = *(const f16x8*)(&Bsm[(nt*16 + (lane & 15))*72 + ko]);
        acc[0][nt] = __builtin_amdgcn_mfma_f32_16x16x32_f16(a0, bf, acc[0][nt], 0, 0, 0);
        acc[1][nt] = __builtin_amdgcn_mfma_f32_16x16x32_f16(a1, bf, acc[1][nt], 0, 0, 0);
      }
    }
  }
  const float bnc = 0.99999500003749969f;  // 1/sqrt(1+1e-5)
#pragma unroll
  for (int mt = 0; mt < 2; ++mt)
#pragma unroll
    for (int nt = 0; nt < 4; ++nt)
#pragma unroll
      for (int r = 0; r < 4; ++r) {
        int m_loc = wave*32 + mt*16 + (lane >> 4)*4 + r;
        int n = n0 + nt*16 + (lane & 15);
        int mg = m0 + m_loc, ob = mg >> 10, ot = mg & 1023;
        float v = acc[mt][nt][r];
        if (mode == 0) {
          v += bias[n];
          outF[(size_t)ob*o_bs + (size_t)ot*o_rs + n] = v;
        } else {
          v = (v + bias[n])*(bng[n]*bnc) + bnb[n];
          v = lrelu(v);
          outH[(size_t)ob*o_bs + (size_t)ot*o_rs + n] = (f16)v;
        }
      }
}

// ---------------- cp head / cardiac params ----------------------------------
__global__ void __launch_bounds__(128) k_cp(const float* w1, const float* b1v, const float* lg,
                                            const float* lb, const float* w2, const float* b2v) {
  __shared__ float ft[512], av[128], s1[128], s2[128];
  int b = blockIdx.x, tid = threadIdx.x;
  for (int i = tid; i < 512; i += 128) ft[i] = g_feats[b*512 + i];
  __syncthreads();
  float acc = b1v[tid];
  for (int k = 0; k < 512; ++k) acc += w1[tid*512 + k]*ft[k];
  s1[tid] = acc; s2[tid] = acc*acc; __syncthreads();
  for (int s = 64; s > 0; s >>= 1) { if (tid < s) { s1[tid]+=s1[tid+s]; s2[tid]+=s2[tid+s]; } __syncthreads(); }
  float m = s1[0]*(1.0f/128.0f), var = s2[0]*(1.0f/128.0f) - m*m;
  av[tid] = lrelu((acc - m)*(1.0f/sqrtf(var + 1e-5f))*lg[tid] + lb[tid]);
  __syncthreads();
  if (tid < 4) {
    float s = b2v[tid];
    for (int i = 0; i < 128; ++i) s += w2[tid*128 + i]*av[i];
    g_cpar[b*4 + tid] = 1.0f/(1.0f + expf(-s));
  }
}

// ---------------- conv3 + enhanced ------------------------------------------
__global__ void __launch_bounds__(256) k_enh(const float* w3, const float* b3) {
  int idx = blockIdx.x*256 + threadIdx.x;
  int b = idx >> 10, t = idx & 1023;
  const f16* xc = g_c3in + (size_t)idx*128u;
  bool hm = (t > 0), hp = (t < 1023);
  float pre = b3[0];
  for (int c = 0; c < 128; ++c) {
    float xm = hm ? (float)xc[c - 128] : 0.0f;
    float x0 = (float)xc[c];
    float xp = hp ? (float)xc[c + 128] : 0.0f;
    pre += xm*w3[c*3] + x0*w3[c*3 + 1] + xp*w3[c*3 + 2];
  }
  float base = tanhf(pre);
  float cp0 = g_cpar[b*4 + 0], cp1 = g_cpar[b*4 + 1], cp2 = g_cpar[b*4 + 2], cp3 = g_cpar[b*4 + 3];
  float freq  = 0.19f + 0.1f*cp0;
  float amp   = 1.0f + 2.0f*cp1;
  float phase = 6.2831853071795864f*cp2;
  float basel = -0.5f + cp3;
  float tl = t*(1.0f/1023.0f);
  float arg = ((6.2831853071795864f*freq)*1024.0f)*tl + phase;
  float card = amp*sinf(arg) + basel;
  g_enh[idx] = 0.1f*base + 0.1f*g_osc[idx] + 0.7f*card + 0.1f*g_smean[t];
}

__global__ void __launch_bounds__(256) k_out(const int* labels, const float* sw,
                                             const float* aw, const float* ab, float* out) {
  int idx = blockIdx.x*256 + threadIdx.x;
  int b = idx >> 10, t = idx & 1023;
  int lab = labels[b];
  float e = g_enh[idx], r;
  if (lab == 1) r = e;
  else if (lab == 2) r = sw[0]*e;
  else if (lab == 3) {
    float em = (t > 0)    ? g_enh[idx - 1] : 0.0f;
    float ep = (t < 1023) ? g_enh[idx + 1] : 0.0f;
    r = aw[0]*em + aw[1]*e + aw[2]*ep + ab[0];
  } else r = 0.0f;
  out[idx] = r;
}

// ---------------- launch -----------------------------------------------------
extern "C" void kernel_launch(void* const* d_in, const int* in_sizes, int n_in,
                              void* d_out, int out_size, void* d_ws, size_t ws_size,
                              hipStream_t stream) {
  const float* z       = (const float*)d_in[0];
  const int*   labels  = (const int*)  d_in[1];
  const float* emb     = (const float*)d_in[2];
  const float* np_w    = (const float*)d_in[3];
  const float* np_b    = (const float*)d_in[4];
  const float* np_ln_g = (const float*)d_in[5];
  const float* np_ln_b = (const float*)d_in[6];
  const float* c_wih   = (const float*)d_in[7];
  const float* c_whh   = (const float*)d_in[8];
  const float* c_bih   = (const float*)d_in[9];
  const float* c_bhh   = (const float*)d_in[10];
  const float* f0_wih  = (const float*)d_in[11];
  const float* f0_whh  = (const float*)d_in[12];
  const float* f0_bih  = (const float*)d_in[13];
  const float* f0_bhh  = (const float*)d_in[14];
  const float* f_wih   = (const float*)d_in[15];
  const float* f_whh   = (const float*)d_in[16];
  const float* f_bih   = (const float*)d_in[17];
  const float* f_bhh   = (const float*)d_in[18];
  const float* osc_w1  = (const float*)d_in[19];
  const float* osc_b1  = (const float*)d_in[20];
  const float* osc_ln_g= (const float*)d_in[21];
  const float* osc_ln_b= (const float*)d_in[22];
  const float* osc_w2  = (const float*)d_in[23];
  const float* osc_b2  = (const float*)d_in[24];
  const float* cp_w1   = (const float*)d_in[25];
  const float* cp_b1   = (const float*)d_in[26];
  const float* cp_ln_g = (const float*)d_in[27];
  const float* cp_ln_b = (const float*)d_in[28];
  const float* cp_w2   = (const float*)d_in[29];
  const float* cp_b2   = (const float*)d_in[30];
  const float* sin_w   = (const float*)d_in[31];
  const float* sin_b   = (const float*)d_in[32];
  const float* conv1_w = (const float*)d_in[33];
  const float* conv1_b = (const float*)d_in[34];
  const float* bn1_g   = (const float*)d_in[35];
  const float* bn1_b   = (const float*)d_in[36];
  const float* conv2_w = (const float*)d_in[37];
  const float* conv2_b = (const float*)d_in[38];
  const float* bn2_g   = (const float*)d_in[39];
  const float* bn2_b   = (const float*)d_in[40];
  const float* conv3_w = (const float*)d_in[41];
  const float* conv3_b = (const float*)d_in[42];
  const float* stress_w= (const float*)d_in[43];
  const float* amuse_w = (const float*)d_in[44];
  const float* amuse_b = (const float*)d_in[45];
  float* out = (float*)d_out;

  k_prep_whh<<<5120, 256, 0, stream>>>(c_whh, f0_whh, f_whh);
  k_prep_wih<<<3072, 256, 0, stream>>>(f_wih, f_bih, f_bhh);
  k_prep_c1 <<<2560, 256, 0, stream>>>(conv1_w);
  k_prep_c2 <<< 384, 256, 0, stream>>>(conv2_w);
  k_zero    <<< 960, 256, 0, stream>>>();
  k_setup1  <<<  64, 256, 0, stream>>>(z, labels, emb, np_w, np_b, np_ln_g, np_ln_b);
  k_xg0     <<< 128,1024, 0, stream>>>(c_wih, c_bih, c_bhh, f0_wih, f0_bih, f0_bhh);
  k_osc     <<<  64, 256, 0, stream>>>(osc_w1, osc_b1, osc_ln_g, osc_ln_b, osc_w2, osc_b2);
  k_sinmean <<<   4, 256, 0, stream>>>(sin_w, sin_b);

  k_lstm    <<< 256, 512, 0, stream>>>(0, 0, 0);   // coarse -> Xpad ch0, feats[0:256]
  k_lstm    <<< 256, 512, 0, stream>>>(1, 1, 1);   // f0 -> fseqA
  for (int l = 0; l < 3; ++l) {                    // f1, f2, f3
    int which = (l == 1) ? 1 : 0;                  // input seq ping-pong
    k_gemm  <<<dim3(512,16), 256, 0, stream>>>(which, l, nullptr, nullptr, nullptr);
    k_lstm  <<< 256, 512, 0, stream>>>(2 + l, 2, 2 + l);  // osel 2,3,4
  }
  k_cp      <<<  64, 128, 0, stream>>>(cp_w1, cp_b1, cp_ln_g, cp_ln_b, cp_w2, cp_b2);
  k_gemm    <<<dim3(512, 4), 256, 0, stream>>>(2, 0, conv1_b, bn1_g, bn1_b);   // conv1
  k_gemm    <<<dim3(512, 2), 256, 0, stream>>>(3, 0, conv2_b, bn2_g, bn2_b);   // conv2
  k_enh     <<< 256, 256, 0, stream>>>(conv3_w, conv3_b);
  k_out     <<< 256, 256, 0, stream>>>(labels, stress_w, amuse_w, amuse_b, out);
}

// Round 2
// 8280.701 us; speedup vs baseline: 1.9864x; 1.1152x over previous
//
#include <hip/hip_runtime.h>

typedef _Float16 f16;
typedef _Float16 f16x2 __attribute__((ext_vector_type(2)));
typedef _Float16 f16x8 __attribute__((ext_vector_type(8)));
typedef float    f32x4 __attribute__((ext_vector_type(4)));

// ---------------- static device scratch (avoids ws_size assumptions) --------
__device__ f16   g_Xpad [64u*1028u*512u];   // conv1 input (B,T+4,512): ch0-255 coarse, 256-511 fine(final)
__device__ f16   g_fseqA[64u*1024u*256u];   // fine sequence ping
__device__ f16   g_fseqB[64u*1024u*256u];   // fine sequence pong
__device__ float g_xg32 [64u*1024u*1024u];  // per-f-layer input projection, permuted gate order, fp32
__device__ f16   g_c2in [64u*1026u*256u];   // conv2 input (B,T+2,256), padded
__device__ f16   g_c3in [64u*1024u*128u];   // conv3 input (B,T,128)
// whh octet-major layout: [L][ko:32][r:1024][kl:8]; k = ko*8+kl, r = u*4+q (orig row g=q*256+u)
__device__ f16   g_whhT2[5u*262144u];
__device__ f16   g_wihB [3u*262144u];       // [l][g'][k] fp16, permuted gate rows (g' = u*4+q)
__device__ float g_biasP[3*1024];           // permuted bih+bhh for f1..f3
__device__ f16   g_B1   [256u*2560u];       // conv1 weight as GEMM B [oc][r*512+ic]
__device__ f16   g_B2   [128u*768u];        // conv2 weight as GEMM B [oc][r*256+ic]
__device__ float g_xg0  [2*64*1024];        // static xg for coarse/f0, permuted [u*4+q]
__device__ float g_cat512[64*512];          // [h, le]
__device__ float g_h    [64*256];
__device__ float g_feats[64*512];           // [coarse.mean, fine.mean]
__device__ float g_osc  [64*1024];
__device__ float g_smean[1024];
__device__ float g_cpar [64*4];             // raw cp sigmoid outputs
__device__ float g_enh  [64*1024];

// ---------------- helpers ---------------------------------------------------
__device__ inline float fdot2f(f16x2 a, f16x2 b, float c) {
#if __has_builtin(__builtin_amdgcn_fdot2)
  return __builtin_amdgcn_fdot2(a, b, c, false);
#else
  return c + (float)a[0]*(float)b[0] + (float)a[1]*(float)b[1];
#endif
}
__device__ inline float sigm_fast(float x) { return 1.0f / (1.0f + __expf(-x)); }
__device__ inline float tanh_fast(float x) { float e = __expf(2.0f*x); return 1.0f - 2.0f/(e + 1.0f); }
__device__ inline float lrelu(float x) { return x < 0.0f ? 0.2f*x : x; }

__device__ __forceinline__ void dot8x(f16x8 w, f16x8 h, float& a) {
  a = fdot2f(__builtin_shufflevector(w, w, 0, 1), __builtin_shufflevector(h, h, 0, 1), a);
  a = fdot2f(__builtin_shufflevector(w, w, 2, 3), __builtin_shufflevector(h, h, 2, 3), a);
  a = fdot2f(__builtin_shufflevector(w, w, 4, 5), __builtin_shufflevector(h, h, 4, 5), a);
  a = fdot2f(__builtin_shufflevector(w, w, 6, 7), __builtin_shufflevector(h, h, 6, 7), a);
}

// ---------------- weight prep ----------------------------------------------
__global__ void __launch_bounds__(256) k_prep_whh(const float* cw, const float* f0w, const float* fw) {
  int bid = blockIdx.x;               // 5*1024
  int L = bid >> 10, g = bid & 1023, k = threadIdx.x;
  const float* src = (L == 0) ? cw : (L == 1) ? f0w : (fw + (size_t)(L-2)*262144u);
  int q = g >> 8, u = g & 255, r = u*4 + q;
  int ko = k >> 3, kl = k & 7;
  g_whhT2[(size_t)L*262144u + (size_t)(ko*1024 + r)*8u + kl] = (f16)src[(size_t)g*256 + k];
}
__global__ void __launch_bounds__(256) k_prep_wih(const float* fwih, const float* fbih, const float* fbhh) {
  int bid = blockIdx.x;               // 3*1024
  int L = bid >> 10, gp = bid & 1023, k = threadIdx.x;
  int j = gp >> 2, q = gp & 3, g = q*256 + j;
  g_wihB[(size_t)L*262144u + (size_t)gp*256u + k] = (f16)fwih[(size_t)L*262144u + (size_t)g*256u + k];
  if (k == 0) g_biasP[L*1024 + gp] = fbih[L*1024 + g] + fbhh[L*1024 + g];
}
__global__ void __launch_bounds__(256) k_prep_c1(const float* w) {
  int idx = blockIdx.x*256 + threadIdx.x;        // 655360
  int oc = idx / 2560, rem = idx % 2560, r = rem / 512, ic = rem % 512;
  g_B1[idx] = (f16)w[(size_t)oc*2560 + (size_t)ic*5 + r];
}
__global__ void __launch_bounds__(256) k_prep_c2(const float* w) {
  int idx = blockIdx.x*256 + threadIdx.x;        // 98304
  int oc = idx / 768, rem = idx % 768, r = rem / 256, ic = rem % 256;
  g_B2[idx] = (f16)w[(size_t)oc*768 + (size_t)ic*3 + r];
}
__global__ void __launch_bounds__(256) k_zero() {
  int idx = blockIdx.x*256 + threadIdx.x;        // 163840
  if (idx < 131072) {   // Xpad pad rows 0,1,1026,1027
    int b = idx >> 11, rem = idx & 2047, rr = rem >> 9, c = rem & 511;
    int row = (rr < 2) ? rr : 1024 + rr;
    g_Xpad[(size_t)b*526336u + (size_t)row*512u + c] = (f16)0.0f;
  } else {              // c2in pad rows 0, 1025
    int i2 = idx - 131072;
    int b = i2 >> 9, rem = i2 & 511, rr = rem >> 8, c = rem & 255;
    int row = rr ? 1025 : 0;
    g_c2in[(size_t)b*262656u + (size_t)row*256u + c] = (f16)0.0f;
  }
}

// ---------------- small front-end ops ---------------------------------------
__global__ void __launch_bounds__(256) k_setup1(const float* z, const int* labels, const float* emb,
                                                const float* npw, const float* npb,
                                                const float* lg, const float* lb) {
  __shared__ float x[384];
  __shared__ float s1[256], s2[256];
  int b = blockIdx.x, tid = threadIdx.x;
  int lab = labels[b];
  for (int i = tid; i < 384; i += 256)
    x[i] = (i < 128) ? z[b*128 + i] : emb[lab*256 + (i - 128)];
  __syncthreads();
  float acc = npb[tid];
  for (int k = 0; k < 384; ++k) acc += npw[tid*384 + k]*x[k];
  s1[tid] = acc; s2[tid] = acc*acc; __syncthreads();
  for (int s = 128; s > 0; s >>= 1) { if (tid < s) { s1[tid]+=s1[tid+s]; s2[tid]+=s2[tid+s]; } __syncthreads(); }
  float m = s1[0]*(1.0f/256.0f), var = s2[0]*(1.0f/256.0f) - m*m;
  float hv = (acc - m)*(1.0f/sqrtf(var + 1e-5f))*lg[tid] + lb[tid];
  hv = lrelu(hv);
  g_h[b*256 + tid] = hv;
  g_cat512[b*512 + tid] = hv;
  g_cat512[b*512 + 256 + tid] = x[128 + tid];
}
__global__ void __launch_bounds__(1024) k_xg0(const float* cwih, const float* cbih, const float* cbhh,
                                              const float* fwih, const float* fbih, const float* fbhh) {
  int bid = blockIdx.x;               // 128 = layer*64+b
  int layer = bid >> 6, b = bid & 63;
  int gp = threadIdx.x, j = gp >> 2, q = gp & 3, g = q*256 + j;
  __shared__ float cat[512];
  if (gp < 512) cat[gp] = g_cat512[b*512 + gp];
  __syncthreads();
  const float* w = layer ? fwih : cwih;
  float acc = layer ? (fbih[g] + fbhh[g]) : (cbih[g] + cbhh[g]);
  for (int k = 0; k < 512; ++k) acc += w[(size_t)g*512 + k]*cat[k];
  g_xg0[(layer*64 + b)*1024 + gp] = acc;
}
__global__ void __launch_bounds__(256) k_osc(const float* w1, const float* b1v, const float* lg,
                                             const float* lb, const float* w2, const float* b2v) {
  __shared__ float hb[256], av[256], s1[256], s2[256];
  int b = blockIdx.x, tid = threadIdx.x;
  hb[tid] = g_h[b*256 + tid];
  __syncthreads();
  float acc = b1v[tid];
  for (int k = 0; k < 256; ++k) acc += w1[tid*256 + k]*hb[k];
  s1[tid] = acc; s2[tid] = acc*acc; __syncthreads();
  for (int s = 128; s > 0; s >>= 1) { if (tid < s) { s1[tid]+=s1[tid+s]; s2[tid]+=s2[tid+s]; } __syncthreads(); }
  float m = s1[0]*(1.0f/256.0f), var = s2[0]*(1.0f/256.0f) - m*m;
  av[tid] = lrelu((acc - m)*(1.0f/sqrtf(var + 1e-5f))*lg[tid] + lb[tid]);
  __syncthreads();
  for (int tt = tid; tt < 1024; tt += 256) {
    float o = b2v[tt];
    for (int i = 0; i < 256; ++i) o += w2[(size_t)tt*256 + i]*av[i];
    g_osc[b*1024 + tt] = tanhf(o);
  }
}
__global__ void __launch_bounds__(256) k_sinmean(const float* sw, const float* sb) {
  int tt = blockIdx.x*256 + threadIdx.x;   // grid 4
  const float F[6] = {0.19f, 0.21f, 0.23f, 0.25f, 0.27f, 0.29f};
  float tl = tt*(1.0f/1023.0f);
  float sc[12];
  for (int j = 0; j < 6; ++j) {
    float p = (6.2831853071795864f * tl) * F[j] * 1024.0f;
    sc[j] = sinf(p); sc[6 + j] = cosf(p);
  }
  float a = 0.0f;
  for (int i = 0; i < 128; ++i) {
    float s = sb[i];
    for (int j = 0; j < 12; ++j) s += sw[i*12 + j]*sc[j];
    a += s;
  }
  g_smean[tt] = a*(1.0f/128.0f);
}

// ---------------- LSTM core: whole weight matrix resident on one CU ---------
// One block per sequence, 512 threads (8 waves, 1 block/CU). Thread tau owns
// permuted gate rows tau and tau+512 (full k). Weight residency:
//   ko 0..7  (128 KB) in LDS   [ko][r][8] (round-0 proven layout)
//   ko 8..31 (384 KB) in VGPRs: wA[24]/wB[24] = 192 regs/thread, loaded once.
// This extends round-1's proven 64-VGPR residency (VGPR_Count=88, no demote)
// to 192; __launch_bounds__(512,2) caps at 256 so 8 waves/CU still fit.
// No cross-block protocol (round-1's LLC mailbox latency ~3670 cy/step was
// the bottleneck); h lives in LDS, 2 barriers/step, deterministic.
__global__ void __launch_bounds__(512, 2) k_lstmA() {
  int bid = blockIdx.x;              // 128: [0,64) coarse, [64,128) f0
  int layer = bid >> 6, b = bid & 63;
  int tau = threadIdx.x;             // 0..511
  const f16* Wc = g_whhT2 + (size_t)layer*262144u;
  __shared__ __align__(16) f16 wlds[65536];      // ko 0..7: [ko][r][8]
  __shared__ __align__(16) f16 hbuf[2][256];
  __shared__ __align__(16) float gbuf[1024];
#pragma unroll
  for (int i = 0; i < 16; ++i) {                 // LDS <- first 128 KB
    int o = i*512 + tau;
    *(f16x8*)(wlds + (size_t)o*8u) = *(const f16x8*)(Wc + (size_t)o*8u);
  }
  // ko 8..31 -> registers (rows tau, tau+512); consecutive lanes -> consecutive 16B
  f16x8 wA[24], wB[24];
  {
    const f16* wp = Wc + (size_t)(8*1024 + tau)*8u;
#pragma unroll
    for (int i = 0; i < 24; ++i) {
      wA[i] = *(const f16x8*)(wp + (size_t)i*8192u);
      wB[i] = *(const f16x8*)(wp + (size_t)i*8192u + 4096u);
    }
  }
  float c0 = 0.0f, sum0 = 0.0f;
  f32x4 xg = {0.f, 0.f, 0.f, 0.f};
  f16* outp = nullptr; int ostride = 0;
  if (tau < 256) {
    xg = *(const f32x4*)(g_xg0 + (layer*64 + b)*1024 + 4*tau);
    hbuf[0][tau] = (f16)0.0f;
    if (layer == 0) { outp = g_Xpad + (size_t)b*526336u + 1024 + tau; ostride = 512; }
    else            { outp = g_fseqA + (size_t)b*262144u + tau;       ostride = 256; }
  }
  __syncthreads();
  int cur = 0;
#pragma unroll 1
  for (int step = 0; step < 1024; ++step) {
    const f16* hb = &hbuf[cur][0];
    float a0 = 0.0f, a1 = 0.0f, b0 = 0.0f, b1 = 0.0f;   // 2 chains/row for ILP
#pragma unroll
    for (int ko = 0; ko < 8; ++ko) {
      f16x8 hv = *(const f16x8*)(hb + ko*8);
      f16x8 wa = *(const f16x8*)(wlds + (size_t)(ko*1024 + tau)*8u);
      f16x8 wb = *(const f16x8*)(wlds + (size_t)(ko*1024 + tau + 512)*8u);
      dot8x(wa, hv, a0); dot8x(wb, hv, b0);
    }
#pragma unroll
    for (int i = 0; i < 24; ++i) {
      f16x8 hv = *(const f16x8*)(hb + 64 + i*8);
      dot8x(wA[i], hv, a1); dot8x(wB[i], hv, b1);
    }
    gbuf[tau] = a0 + a1; gbuf[tau + 512] = b0 + b1;
    __syncthreads();
    if (tau < 256) {
      f32x4 gv = *(const f32x4*)(&gbuf[4*tau]);
      float ii = sigm_fast(gv[0] + xg[0]), ff = sigm_fast(gv[1] + xg[1]);
      float gg = tanh_fast(gv[2] + xg[2]), oo = sigm_fast(gv[3] + xg[3]);
      c0 = ff*c0 + ii*gg;
      float h0 = oo*tanh_fast(c0); sum0 += h0;
      hbuf[cur ^ 1][tau] = (f16)h0;
      outp[(size_t)step*ostride] = (f16)h0;
    }
    __syncthreads();
    cur ^= 1;
  }
  if (tau < 256 && layer == 0) g_feats[b*512 + tau] = sum0*(1.0f/1024.0f);
}

__global__ void __launch_bounds__(512, 2) k_lstmF(int l) {   // l=0..2 -> fine layers f1..f3
  int b = blockIdx.x;               // 64
  int tau = threadIdx.x;            // 0..511
  const f16* Wc = g_whhT2 + (size_t)(2 + l)*262144u;
  __shared__ __align__(16) f16 wlds[65536];
  __shared__ __align__(16) f16 hbuf[2][256];
  __shared__ __align__(16) float gbuf[1024];
#pragma unroll
  for (int i = 0; i < 16; ++i) {
    int o = i*512 + tau;
    *(f16x8*)(wlds + (size_t)o*8u) = *(const f16x8*)(Wc + (size_t)o*8u);
  }
  f16x8 wA[24], wB[24];
  {
    const f16* wp = Wc + (size_t)(8*1024 + tau)*8u;
#pragma unroll
    for (int i = 0; i < 24; ++i) {
      wA[i] = *(const f16x8*)(wp + (size_t)i*8192u);
      wB[i] = *(const f16x8*)(wp + (size_t)i*8192u + 4096u);
    }
  }
  const f32x4* xp = (const f32x4*)(g_xg32 + (size_t)b*1048576u + 4*tau);  // tau<256
  float c0 = 0.0f, sum0 = 0.0f;
  f32x4 xv = {0.f, 0.f, 0.f, 0.f};
  f16* outp = nullptr; int ostride = 0;
  if (tau < 256) {
    xv = xp[0];
    hbuf[0][tau] = (f16)0.0f;
    if (l == 0)      { outp = g_fseqB + (size_t)b*262144u + tau; ostride = 256; }
    else if (l == 1) { outp = g_fseqA + (size_t)b*262144u + tau; ostride = 256; }
    else             { outp = g_Xpad + (size_t)b*526336u + 1024 + 256 + tau; ostride = 512; }
  }
  __syncthreads();
  int cur = 0;
#pragma unroll 1
  for (int step = 0; step < 1024; ++step) {
    const f16* hb = &hbuf[cur][0];
    float a0 = 0.0f, a1 = 0.0f, b0 = 0.0f, b1 = 0.0f;
#pragma unroll
    for (int ko = 0; ko < 8; ++ko) {
      f16x8 hv = *(const f16x8*)(hb + ko*8);
      f16x8 wa = *(const f16x8*)(wlds + (size_t)(ko*1024 + tau)*8u);
      f16x8 wb = *(const f16x8*)(wlds + (size_t)(ko*1024 + tau + 512)*8u);
      dot8x(wa, hv, a0); dot8x(wb, hv, b0);
    }
#pragma unroll
    for (int i = 0; i < 24; ++i) {
      f16x8 hv = *(const f16x8*)(hb + 64 + i*8);
      dot8x(wA[i], hv, a1); dot8x(wB[i], hv, b1);
    }
    gbuf[tau] = a0 + a1; gbuf[tau + 512] = b0 + b1;
    __syncthreads();
    if (tau < 256) {
      f32x4 gv = *(const f32x4*)(&gbuf[4*tau]);
      float ii = sigm_fast(gv[0] + xv[0]), ff = sigm_fast(gv[1] + xv[1]);
      float gg = tanh_fast(gv[2] + xv[2]), oo = sigm_fast(gv[3] + xv[3]);
      c0 = ff*c0 + ii*gg;
      float h0 = oo*tanh_fast(c0); sum0 += h0;
      hbuf[cur ^ 1][tau] = (f16)h0;
      outp[(size_t)step*ostride] = (f16)h0;
      if (step < 1023) xv = xp[(size_t)(step + 1)*256u];
    }
    __syncthreads();
    cur ^= 1;
  }
  if (tau < 256 && l == 2) g_feats[b*512 + 256 + tau] = sum0*(1.0f/1024.0f);
}

// ---------------- generic fp16 MFMA GEMM (implicit conv / xg projection) ----
__global__ void __launch_bounds__(256) k_gemm(int which, int l,
                                              const float* cb, const float* bng, const float* bnb) {
  const f16* A; size_t a_bs; int a_rs, K, N; const f16* Bm; int mode;
  float* outF = nullptr; f16* outH = nullptr; size_t o_bs; int o_rs;
  const float* bias;
  if (which <= 1) {
    A = (which == 0) ? g_fseqA : g_fseqB; a_bs = 262144u; a_rs = 256; K = 256; N = 1024;
    Bm = g_wihB + (size_t)l*262144u; mode = 0; bias = g_biasP + l*1024;
    outF = g_xg32; o_bs = 1048576u; o_rs = 1024;
  } else if (which == 2) {
    A = g_Xpad; a_bs = 526336u; a_rs = 512; K = 2560; N = 256; Bm = g_B1; mode = 1; bias = cb;
    outH = g_c2in + 256; o_bs = 262656u; o_rs = 256;
  } else {
    A = g_c2in; a_bs = 262656u; a_rs = 256; K = 768; N = 128; Bm = g_B2; mode = 1; bias = cb;
    outH = g_c3in; o_bs = 131072u; o_rs = 128;
  }
  int tid = threadIdx.x, wave = tid >> 6, lane = tid & 63;
  int m0 = blockIdx.x*128, n0 = blockIdx.y*64;
  __shared__ __align__(16) f16 Asm[128*72];
  __shared__ __align__(16) f16 Bsm[64*72];
  f32x4 acc[2][4];
#pragma unroll
  for (int i = 0; i < 2; ++i)
#pragma unroll
    for (int jj = 0; jj < 4; ++jj) { f32x4 zz = {0.f,0.f,0.f,0.f}; acc[i][jj] = zz; }
  int ar = tid & 127, ac = (tid >> 7)*32;
  int mrow = m0 + ar, abb = mrow >> 10, att = mrow & 1023;
  const f16* aptr = A + (size_t)abb*a_bs + (size_t)att*a_rs + ac;
  int br = tid & 63, bc = (tid >> 6)*16;
  const f16* bptr = Bm + (size_t)(n0 + br)*K + bc;
  int nkb = K >> 6;
  for (int kb = 0; kb < nkb; ++kb) {
    f16x8 av0 = *(const f16x8*)(aptr + 0);
    f16x8 av1 = *(const f16x8*)(aptr + 8);
    f16x8 av2 = *(const f16x8*)(aptr + 16);
    f16x8 av3 = *(const f16x8*)(aptr + 24);
    f16x8 bv0 = *(const f16x8*)(bptr + 0);
    f16x8 bv1 = *(const f16x8*)(bptr + 8);
    aptr += 64; bptr += 64;
    __syncthreads();
    *(f16x8*)(&Asm[ar*72 + ac + 0])  = av0;
    *(f16x8*)(&Asm[ar*72 + ac + 8])  = av1;
    *(f16x8*)(&Asm[ar*72 + ac + 16]) = av2;
    *(f16x8*)(&Asm[ar*72 + ac + 24]) = av3;
    *(f16x8*)(&Bsm[br*72 + bc + 0])  = bv0;
    *(f16x8*)(&Bsm[br*72 + bc + 8])  = bv1;
    __syncthreads();
#pragma unroll
    for (int ks = 0; ks < 2; ++ks) {
      int ko = ks*32 + (lane >> 4)*8;
      f16x8 a0 = *(const f16x8*)(&Asm[(wave*32 + (lane & 15))*72 + ko]);
      f16x8 a1 = *(const f16x8*)(&Asm[(wave*32 + 16 + (lane & 15))*72 + ko]);
#pragma unroll
      for (int nt = 0; nt < 4; ++nt) {
        f16x8 bf = *(const f16x8*)(&Bsm[(nt*16 + (lane & 15))*72 + ko]);
        acc[0][nt] = __builtin_amdgcn_mfma_f32_16x16x32_f16(a0, bf, acc[0][nt], 0, 0, 0);
        acc[1][nt] = __builtin_amdgcn_mfma_f32_16x16x32_f16(a1, bf, acc[1][nt], 0, 0, 0);
      }
    }
  }
  const float bnc = 0.99999500003749969f;  // 1/sqrt(1+1e-5)
#pragma unroll
  for (int mt = 0; mt < 2; ++mt)
#pragma unroll
    for (int nt = 0; nt < 4; ++nt)
#pragma unroll
      for (int r = 0; r < 4; ++r) {
        int m_loc = wave*32 + mt*16 + (lane >> 4)*4 + r;
        int n = n0 + nt*16 + (lane & 15);
        int mg = m0 + m_loc, ob = mg >> 10, ot = mg & 1023;
        float v = acc[mt][nt][r];
        if (mode == 0) {
          v += bias[n];
          outF[(size_t)ob*o_bs + (size_t)ot*o_rs + n] = v;
        } else {
          v = (v + bias[n])*(bng[n]*bnc) + bnb[n];
          v = lrelu(v);
          outH[(size_t)ob*o_bs + (size_t)ot*o_rs + n] = (f16)v;
        }
      }
}

// ---------------- cp head / cardiac params ----------------------------------
__global__ void __launch_bounds__(128) k_cp(const float* w1, const float* b1v, const float* lg,
                                            const float* lb, const float* w2, const float* b2v) {
  __shared__ float ft[512], av[128], s1[128], s2[128];
  int b = blockIdx.x, tid = threadIdx.x;
  for (int i = tid; i < 512; i += 128) ft[i] = g_feats[b*512 + i];
  __syncthreads();
  float acc = b1v[tid];
  for (int k = 0; k < 512; ++k) acc += w1[tid*512 + k]*ft[k];
  s1[tid] = acc; s2[tid] = acc*acc; __syncthreads();
  for (int s = 64; s > 0; s >>= 1) { if (tid < s) { s1[tid]+=s1[tid+s]; s2[tid]+=s2[tid+s]; } __syncthreads(); }
  float m = s1[0]*(1.0f/128.0f), var = s2[0]*(1.0f/128.0f) - m*m;
  av[tid] = lrelu((acc - m)*(1.0f/sqrtf(var + 1e-5f))*lg[tid] + lb[tid]);
  __syncthreads();
  if (tid < 4) {
    float s = b2v[tid];
    for (int i = 0; i < 128; ++i) s += w2[tid*128 + i]*av[i];
    g_cpar[b*4 + tid] = 1.0f/(1.0f + expf(-s));
  }
}

// ---------------- conv3 + enhanced ------------------------------------------
__global__ void __launch_bounds__(256) k_enh(const float* w3, const float* b3) {
  int idx = blockIdx.x*256 + threadIdx.x;
  int b = idx >> 10, t = idx & 1023;
  const f16* xc = g_c3in + (size_t)idx*128u;
  bool hm = (t > 0), hp = (t < 1023);
  float pre = b3[0];
  for (int c = 0; c < 128; ++c) {
    float xm = hm ? (float)xc[c - 128] : 0.0f;
    float x0 = (float)xc[c];
    float xp = hp ? (float)xc[c + 128] : 0.0f;
    pre += xm*w3[c*3] + x0*w3[c*3 + 1] + xp*w3[c*3 + 2];
  }
  float base = tanhf(pre);
  float cp0 = g_cpar[b*4 + 0], cp1 = g_cpar[b*4 + 1], cp2 = g_cpar[b*4 + 2], cp3 = g_cpar[b*4 + 3];
  float freq  = 0.19f + 0.1f*cp0;
  float amp   = 1.0f + 2.0f*cp1;
  float phase = 6.2831853071795864f*cp2;
  float basel = -0.5f + cp3;
  float tl = t*(1.0f/1023.0f);
  float arg = ((6.2831853071795864f*freq)*1024.0f)*tl + phase;
  float card = amp*sinf(arg) + basel;
  g_enh[idx] = 0.1f*base + 0.1f*g_osc[idx] + 0.7f*card + 0.1f*g_smean[t];
}

__global__ void __launch_bounds__(256) k_out(const int* labels, const float* sw,
                                             const float* aw, const float* ab, float* out) {
  int idx = blockIdx.x*256 + threadIdx.x;
  int b = idx >> 10, t = idx & 1023;
  int lab = labels[b];
  float e = g_enh[idx], r;
  if (lab == 1) r = e;
  else if (lab == 2) r = sw[0]*e;
  else if (lab == 3) {
    float em = (t > 0)    ? g_enh[idx - 1] : 0.0f;
    float ep = (t < 1023) ? g_enh[idx + 1] : 0.0f;
    r = aw[0]*em + aw[1]*e + aw[2]*ep + ab[0];
  } else r = 0.0f;
  out[idx] = r;
}

// ---------------- launch -----------------------------------------------------
extern "C" void kernel_launch(void* const* d_in, const int* in_sizes, int n_in,
                              void* d_out, int out_size, void* d_ws, size_t ws_size,
                              hipStream_t stream) {
  const float* z       = (const float*)d_in[0];
  const int*   labels  = (const int*)  d_in[1];
  const float* emb     = (const float*)d_in[2];
  const float* np_w    = (const float*)d_in[3];
  const float* np_b    = (const float*)d_in[4];
  const float* np_ln_g = (const float*)d_in[5];
  const float* np_ln_b = (const float*)d_in[6];
  const float* c_wih   = (const float*)d_in[7];
  const float* c_whh   = (const float*)d_in[8];
  const float* c_bih   = (const float*)d_in[9];
  const float* c_bhh   = (const float*)d_in[10];
  const float* f0_wih  = (const float*)d_in[11];
  const float* f0_whh  = (const float*)d_in[12];
  const float* f0_bih  = (const float*)d_in[13];
  const float* f0_bhh  = (const float*)d_in[14];
  const float* f_wih   = (const float*)d_in[15];
  const float* f_whh   = (const float*)d_in[16];
  const float* f_bih   = (const float*)d_in[17];
  const float* f_bhh   = (const float*)d_in[18];
  const float* osc_w1  = (const float*)d_in[19];
  const float* osc_b1  = (const float*)d_in[20];
  const float* osc_ln_g= (const float*)d_in[21];
  const float* osc_ln_b= (const float*)d_in[22];
  const float* osc_w2  = (const float*)d_in[23];
  const float* osc_b2  = (const float*)d_in[24];
  const float* cp_w1   = (const float*)d_in[25];
  const float* cp_b1   = (const float*)d_in[26];
  const float* cp_ln_g = (const float*)d_in[27];
  const float* cp_ln_b = (const float*)d_in[28];
  const float* cp_w2   = (const float*)d_in[29];
  const float* cp_b2   = (const float*)d_in[30];
  const float* sin_w   = (const float*)d_in[31];
  const float* sin_b   = (const float*)d_in[32];
  const float* conv1_w = (const float*)d_in[33];
  const float* conv1_b = (const float*)d_in[34];
  const float* bn1_g   = (const float*)d_in[35];
  const float* bn1_b   = (const float*)d_in[36];
  const float* conv2_w = (const float*)d_in[37];
  const float* conv2_b = (const float*)d_in[38];
  const float* bn2_g   = (const float*)d_in[39];
  const float* bn2_b   = (const float*)d_in[40];
  const float* conv3_w = (const float*)d_in[41];
  const float* conv3_b = (const float*)d_in[42];
  const float* stress_w= (const float*)d_in[43];
  const float* amuse_w = (const float*)d_in[44];
  const float* amuse_b = (const float*)d_in[45];
  float* out = (float*)d_out;

  k_prep_whh<<<5120, 256, 0, stream>>>(c_whh, f0_whh, f_whh);
  k_prep_wih<<<3072, 256, 0, stream>>>(f_wih, f_bih, f_bhh);
  k_prep_c1 <<<2560, 256, 0, stream>>>(conv1_w);
  k_prep_c2 <<< 384, 256, 0, stream>>>(conv2_w);
  k_zero    <<< 640, 256, 0, stream>>>();
  k_setup1  <<<  64, 256, 0, stream>>>(z, labels, emb, np_w, np_b, np_ln_g, np_ln_b);
  k_xg0     <<< 128,1024, 0, stream>>>(c_wih, c_bih, c_bhh, f0_wih, f0_bih, f0_bhh);
  k_osc     <<<  64, 256, 0, stream>>>(osc_w1, osc_b1, osc_ln_g, osc_ln_b, osc_w2, osc_b2);
  k_sinmean <<<   4, 256, 0, stream>>>(sin_w, sin_b);

  k_lstmA   <<< 128, 512, 0, stream>>>();                       // coarse + f0 concurrently
  for (int l = 0; l < 3; ++l) {                                 // f1, f2, f3
    int which = (l == 1) ? 1 : 0;                               // input seq ping-pong
    k_gemm  <<<dim3(512,16), 256, 0, stream>>>(which, l, nullptr, nullptr, nullptr);
    k_lstmF <<<  64, 512, 0, stream>>>(l);
  }
  k_cp      <<<  64, 128, 0, stream>>>(cp_w1, cp_b1, cp_ln_g, cp_ln_b, cp_w2, cp_b2);
  k_gemm    <<<dim3(512, 4), 256, 0, stream>>>(2, 0, conv1_b, bn1_g, bn1_b);   // conv1
  k_gemm    <<<dim3(512, 2), 256, 0, stream>>>(3, 0, conv2_b, bn2_g, bn2_b);   // conv2
  k_enh     <<< 256, 256, 0, stream>>>(conv3_w, conv3_b);
  k_out     <<< 256, 256, 0, stream>>>(labels, stress_w, amuse_w, amuse_b, out);
}